// Round 26
// baseline (59.377 us; speedup 1.0000x reference)
//
#include <hip/hip_runtime.h>

// Problem constants: B=8, S=1024, E=128, H=32, DK=4.
constexpr int kS = 1024;
constexpr int NM = 126;  // monomials of degree <=5 in 4 vars: C(9,4)

typedef __fp16 fp16x2 __attribute__((ext_vector_type(2)));
typedef _Float16 half4v __attribute__((ext_vector_type(4)));
typedef _Float16 half8v __attribute__((ext_vector_type(8)));
typedef float float4v __attribute__((ext_vector_type(4)));

// ---------------------------------------------------------------------------
// Feature-map attention (verified R14-R24): P[q,k] = e^{q.k/2}, deg-5
// Chebyshev basis (126 monomials).
//   M[a][c]  = sum_k m_k[a]*vv_k[c]   (vv = [z,1]; col 4 = denominator)
//   num[q][c] = sum_a m_q[a] * (w_a M[a][c]);  out = num[0..3]/num[4].
// R26: featM+featC FUSED per bh (grid 256 x 512 thr): phase A = verified
// featM MFMA structure at 256-token chunks (1 tile/wave, 8 k-steps; sm row
// stride 528B keeps the same free 2-way bank pattern); M lands in LDS Mw
// (f32) — no Mpart round-trip, one fewer launch. Phase B = featC-v7
// verbatim (2 q-chains/thread). R25 lesson: v8's transposed scatter was an
// 8-way-conflict regression — featC stays scalar-v7.
// ---------------------------------------------------------------------------

__device__ __forceinline__ float wcoef(int a0, int a1, int a2, int a3) {
  const float b[6] = {1.0031455f, 1.0010453f, 0.4860342f,
                      0.1641117f, 0.0507286f, 0.0097257f};
  const float f[6] = {1.f, 1.f, 2.f, 6.f, 24.f, 120.f};
  const float p2[6] = {1.f, 2.f, 4.f, 8.f, 16.f, 32.f};
  int n = a0 + a1 + a2 + a3;
  return b[n] * f[n] / (p2[n] * f[a0] * f[a1] * f[a2] * f[a3]);
}

// Canonical graded enumeration of the 126 deg<=5 monomials; shared by all
// kernels so slot s <-> monomial s is consistent (MFMA A/B pairing).
template <class F>
__device__ __forceinline__ void for_each_mono(float z0, float z1, float z2,
                                              float z3, F&& f) {
  int idx = 0;
  float p0 = 1.f;
#pragma unroll
  for (int a0 = 0; a0 <= 5; ++a0) {
    float p1 = p0;
#pragma unroll
    for (int a1 = 0; a1 <= 5 - a0; ++a1) {
      float p2 = p1;
#pragma unroll
      for (int a2 = 0; a2 <= 5 - a0 - a1; ++a2) {
        float p3 = p2;
#pragma unroll
        for (int a3 = 0; a3 <= 5 - a0 - a1 - a2; ++a3) {
          f(idx, p3, a0, a1, a2, a3);
          ++idx;
          p3 *= z3;
        }
        p2 *= z2;
      }
      p1 *= z1;
    }
    p0 *= z0;
  }
}

// ---------------------------------------------------------------------------
// K1: quantum encoder (analytic collapse, verified R1-R25) + W pack fused.
// ---------------------------------------------------------------------------
__global__ __launch_bounds__(256) void qenc_kernel(
    const float4* __restrict__ x4, const float* __restrict__ qp,
    uint2* __restrict__ h16u, const float* __restrict__ W,
    _Float16* __restrict__ wtb) {
  int idx = blockIdx.x * 256 + threadIdx.x;
  if (blockIdx.x < 64) {
    int i = idx;  // 0..16383
    int col = i >> 7, e = i & 127;
    wtb[((e >> 3) << 10) + (col << 3) + (e & 7)] = (_Float16)W[i];
  }
  float4 a = x4[idx];
  float c0 = cosf(a.x + qp[0]);
  float c1 = cosf(a.y + qp[1]);
  float c2 = cosf(a.z + qp[2]);
  float c3 = cosf(a.w + qp[3]);
  float z1 = c0 * c1;
  float z2 = z1 * c2;
  float z3 = z2 * c3;
  float z0 = c1 * c2 * c3;
  union { half4v h; uint2 u; } z;
  z.h.x = (_Float16)z0;
  z.h.y = (_Float16)z1;
  z.h.z = (_Float16)z2;
  z.h.w = (_Float16)z3;
  int b = idx >> 15;
  int s = (idx >> 5) & (kS - 1);
  int head = idx & 31;
  int bh = b * 32 + head;
  h16u[(bh << 10) + s] = z.u;
}

// ---------------------------------------------------------------------------
// K2 fused: one block per bh (512 threads).
// Phase A (featM structure, 256-token chunks): 2 threads/token scatter 63
// monomials each into sm[mi][tok] (consecutive-lane u16 -> free); lo threads
// write vvb cols 0-3. MFMA: 1 row-tile/wave (8 waves = 128 rows), 8 k-steps
// per chunk, acc accumulates over 4 chunks = all 1024 keys.
// Epilogue A: wave w writes its tile's rows to LDS Mw[126][8] (f32).
// Phase B (featC-v7 verbatim): 2 q-chains/thread (q=t, q+512); w folds to
// literals; f32 Mw reads (float4 + b32).
// LDS: sm 67.6KB + vvb 8KB + Mw 4KB ~ 80KB -> 1 block/CU (8 waves).
// ---------------------------------------------------------------------------
__global__ __launch_bounds__(512) void featMC_kernel(
    const _Float16* __restrict__ h16, uint2* __restrict__ o16u2) {
  __shared__ ushort sm[128][264];  // 528B rows = 33 uint4, b128-aligned
  __shared__ ushort vvb[4096];     // [kb(32)][col(16)][j(8)] f16
  __shared__ float Mw[NM][8];
  const int bh = blockIdx.x;
  const int t = threadIdx.x;  // 0..511
  const bool hiH = t >= 256;
  const int tok = t & 255;
  const uint2* __restrict__ hb = (const uint2*)(h16) + (bh << 10);

  // One-time init: sm pad rows (126,127) zero; vvb col4 = 1.0, cols 5-15 = 0.
  for (int i = t; i < 2 * 264; i += 512) sm[126 + i / 264][i % 264] = 0;
  for (int i = t; i < 4096; i += 512)
    vvb[i] = (((i >> 3) & 15) == 4) ? (ushort)0x3C00u : (ushort)0u;

  const int lane = t & 63;
  const int w = t >> 6;  // wave 0..7 -> rows w*16..w*16+15
  const int c = lane & 15, g = lane >> 4;
  float4v acc = {};

  for (int ch = 0; ch < 4; ++ch) {
    __syncthreads();  // covers init on ch=0; phase2->phase1 on later chunks
    // phase 1: monomials + vvb cols 0-3 for this chunk's 256 tokens
    {
      union { uint2 u; half4v h; ushort4 us; } uz;
      uz.u = hb[(ch << 8) + tok];
      float z0 = (float)uz.h.x, z1 = (float)uz.h.y;
      float z2 = (float)uz.h.z, z3 = (float)uz.h.w;
      if (!hiH) {
        int base = ((tok >> 3) << 7) + (tok & 7);
        vvb[base + 0] = uz.us.x;   // col 0
        vvb[base + 8] = uz.us.y;   // col 1
        vvb[base + 16] = uz.us.z;  // col 2
        vvb[base + 24] = uz.us.w;  // col 3
      }
      for_each_mono(z0, z1, z2, z3,
                    [&](int mi, float m, int, int, int, int) {
                      if (hiH ? (mi >= 63) : (mi < 63)) {
                        union { _Float16 h; ushort u; } cv;
                        cv.h = (_Float16)m;
                        sm[mi][tok] = cv.u;
                      }
                    });
    }
    __syncthreads();
    // phase 2: 1 row-tile per wave x 8 k-steps (256 keys), verified pairing
    {
      const uint4* __restrict__ vvb4 = (const uint4*)vvb;
      const uint4* __restrict__ arow4 = (const uint4*)&sm[(w << 4) + c][0];
      union U4H { uint4 u; half8v h; };
#pragma unroll
      for (int ks = 0; ks < 8; ++ks) {
        U4H ub, ua;
        ub.u = vvb4[(((ks << 2) + g) << 4) + c];
        ua.u = arow4[(ks << 2) + g];
        acc = __builtin_amdgcn_mfma_f32_16x16x32_f16(ua.h, ub.h, acc, 0, 0, 0);
      }
    }
  }

  // epilogue A: C/D row = w*16 + g*4 + reg, col = c -> LDS Mw (raw M, f32)
  if (c < 5) {
#pragma unroll
    for (int reg = 0; reg < 4; ++reg) {
      int row = (w << 4) + (g << 2) + reg;
      if (row < NM) Mw[row][c] = acc[reg];
    }
  }
  __syncthreads();

  // phase B (featC-v7): 2 q-chains per thread: q0 = t, q1 = t + 512
  const int q0 = t;
  union { uint2 u; half4v h; } ua_, ub_;
  ua_.u = hb[q0];
  ub_.u = hb[q0 + 512];
  float xa0 = (float)ua_.h.x, xa1 = (float)ua_.h.y;
  float xa2 = (float)ua_.h.z, xa3 = (float)ua_.h.w;
  float xb0 = (float)ub_.h.x, xb1 = (float)ub_.h.y;
  float xb2 = (float)ub_.h.z, xb3 = (float)ub_.h.w;

  float nA0 = 0.f, nA1 = 0.f, nA2 = 0.f, nA3 = 0.f, dA = 0.f;
  float nB0 = 0.f, nB1 = 0.f, nB2 = 0.f, nB3 = 0.f, dB = 0.f;

  int idx = 0;
  float pa0 = 1.f, pb0 = 1.f;
#pragma unroll
  for (int a0 = 0; a0 <= 5; ++a0) {
    float pa1 = pa0, pb1 = pb0;
#pragma unroll
    for (int a1 = 0; a1 <= 5 - a0; ++a1) {
      float pa2 = pa1, pb2 = pb1;
#pragma unroll
      for (int a2 = 0; a2 <= 5 - a0 - a1; ++a2) {
        float pa3 = pa2, pb3 = pb2;
#pragma unroll
        for (int a3 = 0; a3 <= 5 - a0 - a1 - a2; ++a3) {
          float wc = wcoef(a0, a1, a2, a3);  // literal after unroll
          float wa = pa3 * wc, wb = pb3 * wc;
          float4 M4 = *(const float4*)&Mw[idx][0];
          float M5 = Mw[idx][4];
          nA0 += wa * M4.x; nA1 += wa * M4.y;
          nA2 += wa * M4.z; nA3 += wa * M4.w;
          dA += wa * M5;
          nB0 += wb * M4.x; nB1 += wb * M4.y;
          nB2 += wb * M4.z; nB3 += wb * M4.w;
          dB += wb * M5;
          ++idx;
          pa3 *= xa3; pb3 *= xb3;
        }
        pa2 *= xa2; pb2 *= xb2;
      }
      pa1 *= xa1; pb1 *= xb1;
    }
    pa0 *= xa0; pb0 *= xb0;
  }

  const int b_ = bh >> 5, head = bh & 31;
  {
    float inv = 1.0f / dA;
    union { fp16x2 p[2]; uint2 u; } res;
    res.p[0] = __builtin_amdgcn_cvt_pkrtz(nA0 * inv, nA1 * inv);
    res.p[1] = __builtin_amdgcn_cvt_pkrtz(nA2 * inv, nA3 * inv);
    o16u2[(((b_ << 10) + q0) << 5) + head] = res.u;
  }
  {
    float inv = 1.0f / dB;
    union { fp16x2 p[2]; uint2 u; } res;
    res.p[0] = __builtin_amdgcn_cvt_pkrtz(nB0 * inv, nB1 * inv);
    res.p[1] = __builtin_amdgcn_cvt_pkrtz(nB2 * inv, nB3 * inv);
    o16u2[(((b_ << 10) + q0 + 512) << 5) + head] = res.u;
  }
}

// ---------------------------------------------------------------------------
// K3: combine GEMM out[8192][128] = o16 @ W^T via mfma_f32_16x16x32_f16.
// (verified R6-R25: ~3 us)
// ---------------------------------------------------------------------------
__global__ __launch_bounds__(256) void combine_kernel(
    const _Float16* __restrict__ o16, const _Float16* __restrict__ wtb,
    float* __restrict__ out) {
  const int lane = threadIdx.x & 63;
  const int wv = threadIdx.x >> 6;
  const int job = blockIdx.x * 4 + wv;  // 0..4095
  const int rt = job >> 3, ct = job & 7;
  const int c = lane & 15, g = lane >> 4;
  const uint4* a4 = (const uint4*)o16;
  const uint4* b4 = (const uint4*)wtb;
  const int arow = (rt << 4) + c;
  union U4H { uint4 u; half8v h; };
  float4v acc = {};
#pragma unroll
  for (int t = 0; t < 4; ++t) {
    U4H ua, ub;
    ua.u = a4[(arow << 4) + (t << 2) + g];
    ub.u = b4[(((t << 2) + g) << 7) + (ct << 4) + c];
    acc = __builtin_amdgcn_mfma_f32_16x16x32_f16(ua.h, ub.h, acc, 0, 0, 0);
  }
  const int orow = (rt << 4) + (g << 2);
  const int ocol = (ct << 4) + c;
#pragma unroll
  for (int reg = 0; reg < 4; ++reg)
    out[(orow + reg) * 128 + ocol] = acc[reg];
}

extern "C" void kernel_launch(void* const* d_in, const int* in_sizes, int n_in,
                              void* d_out, int out_size, void* d_ws,
                              size_t ws_size, hipStream_t stream) {
  const float* x = (const float*)d_in[0];   // [8,1024,128] f32
  const float* qp = (const float*)d_in[1];  // [1,4] f32
  const float* W = (const float*)d_in[2];   // [128,128] f32
  float* out = (float*)d_out;               // [8,1024,128] f32

  char* ws = (char*)d_ws;
  _Float16* h16 = (_Float16*)ws;                // [256][1024][4] f16 = 2 MB
  _Float16* o16 = (_Float16*)(ws + (2 << 20));  // [8192][128] f16 = 2 MB
  _Float16* wtb = (_Float16*)(ws + (4 << 20));  // [16][128][8] f16 = 32 KB

  qenc_kernel<<<1024, 256, 0, stream>>>((const float4*)x, qp, (uint2*)h16, W,
                                        wtb);
  featMC_kernel<<<256, 512, 0, stream>>>(h16, (uint2*)o16);
  combine_kernel<<<1024, 256, 0, stream>>>(o16, wtb, out);
}

// Round 27
// 58.709 us; speedup vs baseline: 1.0114x; 1.0114x over previous
//
#include <hip/hip_runtime.h>

// Problem constants: B=8, S=1024, E=128, H=32, DK=4.
constexpr int kS = 1024;
constexpr int NM = 126;  // monomials of degree <=5 in 4 vars: C(9,4)

typedef __fp16 fp16x2 __attribute__((ext_vector_type(2)));
typedef _Float16 half4v __attribute__((ext_vector_type(4)));
typedef _Float16 half8v __attribute__((ext_vector_type(8)));
typedef float float4v __attribute__((ext_vector_type(4)));

// ---------------------------------------------------------------------------
// Feature-map attention (verified R14-R24): P[q,k] = e^{q.k/2}, deg-5
// Chebyshev basis (126 monomials).
//   M[a][c]  = sum_k m_k[a]*vv_k[c]   (vv = [z,1]; col 4 = denominator)
//   num[q][c] = sum_a m_q[a] * (w_a M[a][c]);  out = num[0..3]/num[4].
// R26: featM+featC FUSED per bh (grid 256 x 512 thr): phase A = verified
// featM MFMA structure at 256-token chunks (1 tile/wave, 8 k-steps; sm row
// stride 528B keeps the same free 2-way bank pattern); M lands in LDS Mw
// (f32) — no Mpart round-trip, one fewer launch. Phase B = featC-v7
// verbatim (2 q-chains/thread). R25 lesson: v8's transposed scatter was an
// 8-way-conflict regression — featC stays scalar-v7.
// ---------------------------------------------------------------------------

__device__ __forceinline__ float wcoef(int a0, int a1, int a2, int a3) {
  const float b[6] = {1.0031455f, 1.0010453f, 0.4860342f,
                      0.1641117f, 0.0507286f, 0.0097257f};
  const float f[6] = {1.f, 1.f, 2.f, 6.f, 24.f, 120.f};
  const float p2[6] = {1.f, 2.f, 4.f, 8.f, 16.f, 32.f};
  int n = a0 + a1 + a2 + a3;
  return b[n] * f[n] / (p2[n] * f[a0] * f[a1] * f[a2] * f[a3]);
}

// Canonical graded enumeration of the 126 deg<=5 monomials; shared by all
// kernels so slot s <-> monomial s is consistent (MFMA A/B pairing).
template <class F>
__device__ __forceinline__ void for_each_mono(float z0, float z1, float z2,
                                              float z3, F&& f) {
  int idx = 0;
  float p0 = 1.f;
#pragma unroll
  for (int a0 = 0; a0 <= 5; ++a0) {
    float p1 = p0;
#pragma unroll
    for (int a1 = 0; a1 <= 5 - a0; ++a1) {
      float p2 = p1;
#pragma unroll
      for (int a2 = 0; a2 <= 5 - a0 - a1; ++a2) {
        float p3 = p2;
#pragma unroll
        for (int a3 = 0; a3 <= 5 - a0 - a1 - a2; ++a3) {
          f(idx, p3, a0, a1, a2, a3);
          ++idx;
          p3 *= z3;
        }
        p2 *= z2;
      }
      p1 *= z1;
    }
    p0 *= z0;
  }
}

// ---------------------------------------------------------------------------
// K1: quantum encoder (analytic collapse, verified R1-R25) + W pack fused.
// ---------------------------------------------------------------------------
__global__ __launch_bounds__(256) void qenc_kernel(
    const float4* __restrict__ x4, const float* __restrict__ qp,
    uint2* __restrict__ h16u, const float* __restrict__ W,
    _Float16* __restrict__ wtb) {
  int idx = blockIdx.x * 256 + threadIdx.x;
  if (blockIdx.x < 64) {
    int i = idx;  // 0..16383
    int col = i >> 7, e = i & 127;
    wtb[((e >> 3) << 10) + (col << 3) + (e & 7)] = (_Float16)W[i];
  }
  float4 a = x4[idx];
  float c0 = cosf(a.x + qp[0]);
  float c1 = cosf(a.y + qp[1]);
  float c2 = cosf(a.z + qp[2]);
  float c3 = cosf(a.w + qp[3]);
  float z1 = c0 * c1;
  float z2 = z1 * c2;
  float z3 = z2 * c3;
  float z0 = c1 * c2 * c3;
  union { half4v h; uint2 u; } z;
  z.h.x = (_Float16)z0;
  z.h.y = (_Float16)z1;
  z.h.z = (_Float16)z2;
  z.h.w = (_Float16)z3;
  int b = idx >> 15;
  int s = (idx >> 5) & (kS - 1);
  int head = idx & 31;
  int bh = b * 32 + head;
  h16u[(bh << 10) + s] = z.u;
}

// ---------------------------------------------------------------------------
// K2 fused: one block per bh (512 threads).
// Phase A (featM structure, 256-token chunks): 2 threads/token scatter 63
// monomials each into sm[mi][tok] (consecutive-lane u16 -> free); lo threads
// write vvb cols 0-3. MFMA: 1 row-tile/wave (8 waves = 128 rows), 8 k-steps
// per chunk, acc accumulates over 4 chunks = all 1024 keys.
// Epilogue A: wave w writes its tile's rows to LDS Mw[126][8] (f32).
// Phase B (featC-v7 verbatim): 2 q-chains/thread (q=t, q+512); w folds to
// literals; f32 Mw reads (float4 + b32).
// LDS: sm 67.6KB + vvb 8KB + Mw 4KB ~ 80KB -> 1 block/CU (8 waves).
// ---------------------------------------------------------------------------
__global__ __launch_bounds__(512) void featMC_kernel(
    const _Float16* __restrict__ h16, uint2* __restrict__ o16u2) {
  __shared__ ushort sm[128][264];  // 528B rows = 33 uint4, b128-aligned
  __shared__ ushort vvb[4096];     // [kb(32)][col(16)][j(8)] f16
  __shared__ float Mw[NM][8];
  const int bh = blockIdx.x;
  const int t = threadIdx.x;  // 0..511
  const bool hiH = t >= 256;
  const int tok = t & 255;
  const uint2* __restrict__ hb = (const uint2*)(h16) + (bh << 10);

  // One-time init: sm pad rows (126,127) zero; vvb col4 = 1.0, cols 5-15 = 0.
  for (int i = t; i < 2 * 264; i += 512) sm[126 + i / 264][i % 264] = 0;
  for (int i = t; i < 4096; i += 512)
    vvb[i] = (((i >> 3) & 15) == 4) ? (ushort)0x3C00u : (ushort)0u;

  const int lane = t & 63;
  const int w = t >> 6;  // wave 0..7 -> rows w*16..w*16+15
  const int c = lane & 15, g = lane >> 4;
  float4v acc = {};

  for (int ch = 0; ch < 4; ++ch) {
    __syncthreads();  // covers init on ch=0; phase2->phase1 on later chunks
    // phase 1: monomials + vvb cols 0-3 for this chunk's 256 tokens
    {
      union { uint2 u; half4v h; ushort4 us; } uz;
      uz.u = hb[(ch << 8) + tok];
      float z0 = (float)uz.h.x, z1 = (float)uz.h.y;
      float z2 = (float)uz.h.z, z3 = (float)uz.h.w;
      if (!hiH) {
        int base = ((tok >> 3) << 7) + (tok & 7);
        vvb[base + 0] = uz.us.x;   // col 0
        vvb[base + 8] = uz.us.y;   // col 1
        vvb[base + 16] = uz.us.z;  // col 2
        vvb[base + 24] = uz.us.w;  // col 3
      }
      for_each_mono(z0, z1, z2, z3,
                    [&](int mi, float m, int, int, int, int) {
                      if (hiH ? (mi >= 63) : (mi < 63)) {
                        union { _Float16 h; ushort u; } cv;
                        cv.h = (_Float16)m;
                        sm[mi][tok] = cv.u;
                      }
                    });
    }
    __syncthreads();
    // phase 2: 1 row-tile per wave x 8 k-steps (256 keys), verified pairing
    {
      const uint4* __restrict__ vvb4 = (const uint4*)vvb;
      const uint4* __restrict__ arow4 = (const uint4*)&sm[(w << 4) + c][0];
      union U4H { uint4 u; half8v h; };
#pragma unroll
      for (int ks = 0; ks < 8; ++ks) {
        U4H ub, ua;
        ub.u = vvb4[(((ks << 2) + g) << 4) + c];
        ua.u = arow4[(ks << 2) + g];
        acc = __builtin_amdgcn_mfma_f32_16x16x32_f16(ua.h, ub.h, acc, 0, 0, 0);
      }
    }
  }

  // epilogue A: C/D row = w*16 + g*4 + reg, col = c -> LDS Mw (raw M, f32)
  if (c < 5) {
#pragma unroll
    for (int reg = 0; reg < 4; ++reg) {
      int row = (w << 4) + (g << 2) + reg;
      if (row < NM) Mw[row][c] = acc[reg];
    }
  }
  __syncthreads();

  // phase B (featC-v7): 2 q-chains per thread: q0 = t, q1 = t + 512
  const int q0 = t;
  union { uint2 u; half4v h; } ua_, ub_;
  ua_.u = hb[q0];
  ub_.u = hb[q0 + 512];
  float xa0 = (float)ua_.h.x, xa1 = (float)ua_.h.y;
  float xa2 = (float)ua_.h.z, xa3 = (float)ua_.h.w;
  float xb0 = (float)ub_.h.x, xb1 = (float)ub_.h.y;
  float xb2 = (float)ub_.h.z, xb3 = (float)ub_.h.w;

  float nA0 = 0.f, nA1 = 0.f, nA2 = 0.f, nA3 = 0.f, dA = 0.f;
  float nB0 = 0.f, nB1 = 0.f, nB2 = 0.f, nB3 = 0.f, dB = 0.f;

  int idx = 0;
  float pa0 = 1.f, pb0 = 1.f;
#pragma unroll
  for (int a0 = 0; a0 <= 5; ++a0) {
    float pa1 = pa0, pb1 = pb0;
#pragma unroll
    for (int a1 = 0; a1 <= 5 - a0; ++a1) {
      float pa2 = pa1, pb2 = pb1;
#pragma unroll
      for (int a2 = 0; a2 <= 5 - a0 - a1; ++a2) {
        float pa3 = pa2, pb3 = pb2;
#pragma unroll
        for (int a3 = 0; a3 <= 5 - a0 - a1 - a2; ++a3) {
          float wc = wcoef(a0, a1, a2, a3);  // literal after unroll
          float wa = pa3 * wc, wb = pb3 * wc;
          float4 M4 = *(const float4*)&Mw[idx][0];
          float M5 = Mw[idx][4];
          nA0 += wa * M4.x; nA1 += wa * M4.y;
          nA2 += wa * M4.z; nA3 += wa * M4.w;
          dA += wa * M5;
          nB0 += wb * M4.x; nB1 += wb * M4.y;
          nB2 += wb * M4.z; nB3 += wb * M4.w;
          dB += wb * M5;
          ++idx;
          pa3 *= xa3; pb3 *= xb3;
        }
        pa2 *= xa2; pb2 *= xb2;
      }
      pa1 *= xa1; pb1 *= xb1;
    }
    pa0 *= xa0; pb0 *= xb0;
  }

  const int b_ = bh >> 5, head = bh & 31;
  {
    float inv = 1.0f / dA;
    union { fp16x2 p[2]; uint2 u; } res;
    res.p[0] = __builtin_amdgcn_cvt_pkrtz(nA0 * inv, nA1 * inv);
    res.p[1] = __builtin_amdgcn_cvt_pkrtz(nA2 * inv, nA3 * inv);
    o16u2[(((b_ << 10) + q0) << 5) + head] = res.u;
  }
  {
    float inv = 1.0f / dB;
    union { fp16x2 p[2]; uint2 u; } res;
    res.p[0] = __builtin_amdgcn_cvt_pkrtz(nB0 * inv, nB1 * inv);
    res.p[1] = __builtin_amdgcn_cvt_pkrtz(nB2 * inv, nB3 * inv);
    o16u2[(((b_ << 10) + q0 + 512) << 5) + head] = res.u;
  }
}

// ---------------------------------------------------------------------------
// K3: combine GEMM out[8192][128] = o16 @ W^T via mfma_f32_16x16x32_f16.
// (verified R6-R25: ~3 us)
// ---------------------------------------------------------------------------
__global__ __launch_bounds__(256) void combine_kernel(
    const _Float16* __restrict__ o16, const _Float16* __restrict__ wtb,
    float* __restrict__ out) {
  const int lane = threadIdx.x & 63;
  const int wv = threadIdx.x >> 6;
  const int job = blockIdx.x * 4 + wv;  // 0..4095
  const int rt = job >> 3, ct = job & 7;
  const int c = lane & 15, g = lane >> 4;
  const uint4* a4 = (const uint4*)o16;
  const uint4* b4 = (const uint4*)wtb;
  const int arow = (rt << 4) + c;
  union U4H { uint4 u; half8v h; };
  float4v acc = {};
#pragma unroll
  for (int t = 0; t < 4; ++t) {
    U4H ua, ub;
    ua.u = a4[(arow << 4) + (t << 2) + g];
    ub.u = b4[(((t << 2) + g) << 7) + (ct << 4) + c];
    acc = __builtin_amdgcn_mfma_f32_16x16x32_f16(ua.h, ub.h, acc, 0, 0, 0);
  }
  const int orow = (rt << 4) + (g << 2);
  const int ocol = (ct << 4) + c;
#pragma unroll
  for (int reg = 0; reg < 4; ++reg)
    out[(orow + reg) * 128 + ocol] = acc[reg];
}

extern "C" void kernel_launch(void* const* d_in, const int* in_sizes, int n_in,
                              void* d_out, int out_size, void* d_ws,
                              size_t ws_size, hipStream_t stream) {
  const float* x = (const float*)d_in[0];   // [8,1024,128] f32
  const float* qp = (const float*)d_in[1];  // [1,4] f32
  const float* W = (const float*)d_in[2];   // [128,128] f32
  float* out = (float*)d_out;               // [8,1024,128] f32

  char* ws = (char*)d_ws;
  _Float16* h16 = (_Float16*)ws;                // [256][1024][4] f16 = 2 MB
  _Float16* o16 = (_Float16*)(ws + (2 << 20));  // [8192][128] f16 = 2 MB
  _Float16* wtb = (_Float16*)(ws + (4 << 20));  // [16][128][8] f16 = 32 KB

  qenc_kernel<<<1024, 256, 0, stream>>>((const float4*)x, qp, (uint2*)h16, W,
                                        wtb);
  featMC_kernel<<<256, 512, 0, stream>>>(h16, (uint2*)o16);
  combine_kernel<<<1024, 256, 0, stream>>>(o16, wtb, out);
}

// Round 28
// 32.833 us; speedup vs baseline: 1.8085x; 1.7881x over previous
//
#include <hip/hip_runtime.h>

// Problem constants: B=8, S=1024, E=128, H=32, DK=4.
constexpr int kS = 1024;
constexpr int NM = 126;  // monomials of degree <=5 in 4 vars: C(9,4)

typedef __fp16 fp16x2 __attribute__((ext_vector_type(2)));
typedef _Float16 half4v __attribute__((ext_vector_type(4)));
typedef _Float16 half8v __attribute__((ext_vector_type(8)));
typedef float float4v __attribute__((ext_vector_type(4)));

// ---------------------------------------------------------------------------
// Feature-map attention (verified R14-R24): P[q,k] = e^{q.k/2}, deg-5
// Chebyshev basis (126 monomials).
//   M[a][c]  = sum_k m_k[a]*vv_k[c]   (vv = [z,1]; col 4 = denominator)
//   num[q][c] = sum_a m_q[a] * (w_a M[a][c]);  out = num[0..3]/num[4].
// R28 = R24 VERBATIM REVERT (best verified: 31.4us). Experiment record:
//   R25 featC->MFMA: +10us (transposed scatter = 8-way bank conflict)
//   R26/27 featM+featC fusion: +27us (80KB LDS -> 1 block/CU; scalar phase
//     lost 4x occupancy — occupancy beats launch-gap savings)
// Remaining ~19us is dispatch/graph-replay floor at 4 launches.
// ---------------------------------------------------------------------------

__device__ __forceinline__ float wcoef(int a0, int a1, int a2, int a3) {
  const float b[6] = {1.0031455f, 1.0010453f, 0.4860342f,
                      0.1641117f, 0.0507286f, 0.0097257f};
  const float f[6] = {1.f, 1.f, 2.f, 6.f, 24.f, 120.f};
  const float p2[6] = {1.f, 2.f, 4.f, 8.f, 16.f, 32.f};
  int n = a0 + a1 + a2 + a3;
  return b[n] * f[n] / (p2[n] * f[a0] * f[a1] * f[a2] * f[a3]);
}

// Canonical graded enumeration of the 126 deg<=5 monomials; shared by all
// kernels so slot s <-> monomial s is consistent (MFMA A/B pairing).
template <class F>
__device__ __forceinline__ void for_each_mono(float z0, float z1, float z2,
                                              float z3, F&& f) {
  int idx = 0;
  float p0 = 1.f;
#pragma unroll
  for (int a0 = 0; a0 <= 5; ++a0) {
    float p1 = p0;
#pragma unroll
    for (int a1 = 0; a1 <= 5 - a0; ++a1) {
      float p2 = p1;
#pragma unroll
      for (int a2 = 0; a2 <= 5 - a0 - a1; ++a2) {
        float p3 = p2;
#pragma unroll
        for (int a3 = 0; a3 <= 5 - a0 - a1 - a2; ++a3) {
          f(idx, p3, a0, a1, a2, a3);
          ++idx;
          p3 *= z3;
        }
        p2 *= z2;
      }
      p1 *= z1;
    }
    p0 *= z0;
  }
}

// ---------------------------------------------------------------------------
// K1: quantum encoder (analytic collapse, verified R1-R24) + W pack fused.
// ---------------------------------------------------------------------------
__global__ __launch_bounds__(256) void qenc_kernel(
    const float4* __restrict__ x4, const float* __restrict__ qp,
    uint2* __restrict__ h16u, const float* __restrict__ W,
    _Float16* __restrict__ wtb) {
  int idx = blockIdx.x * 256 + threadIdx.x;
  if (blockIdx.x < 64) {
    int i = idx;  // 0..16383
    int col = i >> 7, e = i & 127;
    wtb[((e >> 3) << 10) + (col << 3) + (e & 7)] = (_Float16)W[i];
  }
  float4 a = x4[idx];
  float c0 = cosf(a.x + qp[0]);
  float c1 = cosf(a.y + qp[1]);
  float c2 = cosf(a.z + qp[2]);
  float c3 = cosf(a.w + qp[3]);
  float z1 = c0 * c1;
  float z2 = z1 * c2;
  float z3 = z2 * c3;
  float z0 = c1 * c2 * c3;
  union { half4v h; uint2 u; } z;
  z.h.x = (_Float16)z0;
  z.h.y = (_Float16)z1;
  z.h.z = (_Float16)z2;
  z.h.w = (_Float16)z3;
  int b = idx >> 15;
  int s = (idx >> 5) & (kS - 1);
  int head = idx & 31;
  int bh = b * 32 + head;
  h16u[(bh << 10) + s] = z.u;
}

// ---------------------------------------------------------------------------
// K2a (R21/R22-verbatim, verified): M[bh][half][row][c] via MFMA phase 2.
// ---------------------------------------------------------------------------
__global__ __launch_bounds__(256) void featM_kernel(
    const _Float16* __restrict__ h16, float* __restrict__ Mpart) {
  __shared__ ushort sm[128][136];  // 272B rows = 17 uint4, b128-aligned
  __shared__ ushort vvb[2048];     // [kb(16)][col(16)][j(8)] f16
  const int bh = blockIdx.x >> 1;
  const int half = blockIdx.x & 1;
  const int t = threadIdx.x;
  const bool hiH = t >= 128;
  const int tok = t & 127;
  const uint2* __restrict__ hb = (const uint2*)(h16) + (bh << 10) + (half << 9);

  // One-time init: sm pad rows (126,127) zero; vvb col4 = 1.0, cols 5-15 = 0.
  for (int i = t; i < 2 * 136; i += 256) sm[126 + i / 136][i % 136] = 0;
  for (int i = t; i < 2048; i += 256)
    vvb[i] = (((i >> 3) & 15) == 4) ? (ushort)0x3C00u : (ushort)0u;

  const int lane = t & 63;
  const int w = t >> 6;
  const int c = lane & 15, g = lane >> 4;
  float4v acc[2] = {};

  for (int ch = 0; ch < 4; ++ch) {
    __syncthreads();  // covers init on ch=0; phase2->phase1 on later chunks
    {
      union { uint2 u; half4v h; ushort4 us; } uz;
      uz.u = hb[(ch << 7) + tok];
      float z0 = (float)uz.h.x, z1 = (float)uz.h.y;
      float z2 = (float)uz.h.z, z3 = (float)uz.h.w;
      if (!hiH) {
        int base = ((tok >> 3) << 7) + (tok & 7);
        vvb[base + 0] = uz.us.x;   // col 0
        vvb[base + 8] = uz.us.y;   // col 1
        vvb[base + 16] = uz.us.z;  // col 2
        vvb[base + 24] = uz.us.w;  // col 3
      }
      for_each_mono(z0, z1, z2, z3,
                    [&](int mi, float m, int, int, int, int) {
                      if (hiH ? (mi >= 63) : (mi < 63)) {
                        union { _Float16 h; ushort u; } cv;
                        cv.h = (_Float16)m;
                        sm[mi][tok] = cv.u;
                      }
                    });
    }
    __syncthreads();
    {
      const uint4* __restrict__ vvb4 = (const uint4*)vvb;
      union U4H { uint4 u; half8v h; };
#pragma unroll
      for (int ks = 0; ks < 4; ++ks) {
        U4H ub;
        ub.u = vvb4[(((ks << 2) + g) << 4) + c];
#pragma unroll
        for (int tl = 0; tl < 2; ++tl) {
          const uint4* arow4 = (const uint4*)&sm[(w << 5) + (tl << 4) + c][0];
          U4H ua;
          ua.u = arow4[(ks << 2) + g];
          acc[tl] = __builtin_amdgcn_mfma_f32_16x16x32_f16(ua.h, ub.h,
                                                           acc[tl], 0, 0, 0);
        }
      }
    }
  }

  if (c < 5) {
    float* mp = Mpart + ((bh << 1) + half) * NM * 5;
#pragma unroll
    for (int tl = 0; tl < 2; ++tl) {
#pragma unroll
      for (int reg = 0; reg < 4; ++reg) {
        int row = (w << 5) + (tl << 4) + (g << 2) + reg;
        if (row < NM) mp[row * 5 + c] = acc[tl][reg];
      }
    }
  }
}

// ---------------------------------------------------------------------------
// K2b v7 (verified R24): out_num[q] = (w o m_q) . Mw, TWO q-rows per thread
// (q, q+256). f32 Mw (float4 + b32 reads). Block = (bh, half), grid 512.
// ---------------------------------------------------------------------------
__global__ __launch_bounds__(256) void featC_kernel(
    const _Float16* __restrict__ h16, const float* __restrict__ Mpart,
    uint2* __restrict__ o16u2) {
  __shared__ float Mw[NM][8];
  const int bh = blockIdx.x >> 1;
  const int qh = blockIdx.x & 1;
  const int t = threadIdx.x;
  if (t < NM) {
    const float* m0 = Mpart + ((bh << 1) * NM + t) * 5;
    const float* m1 = m0 + NM * 5;
#pragma unroll
    for (int c = 0; c < 5; ++c) Mw[t][c] = m0[c] + m1[c];
  }
  __syncthreads();

  const int q0 = (qh << 9) + t;  // second row: q0 + 256
  const uint2* hz = (const uint2*)h16 + (bh << 10);
  union { uint2 u; half4v h; } ua, ub;
  ua.u = hz[q0];
  ub.u = hz[q0 + 256];
  float xa0 = (float)ua.h.x, xa1 = (float)ua.h.y;
  float xa2 = (float)ua.h.z, xa3 = (float)ua.h.w;
  float xb0 = (float)ub.h.x, xb1 = (float)ub.h.y;
  float xb2 = (float)ub.h.z, xb3 = (float)ub.h.w;

  float nA0 = 0.f, nA1 = 0.f, nA2 = 0.f, nA3 = 0.f, dA = 0.f;
  float nB0 = 0.f, nB1 = 0.f, nB2 = 0.f, nB3 = 0.f, dB = 0.f;

  int idx = 0;
  float pa0 = 1.f, pb0 = 1.f;
#pragma unroll
  for (int a0 = 0; a0 <= 5; ++a0) {
    float pa1 = pa0, pb1 = pb0;
#pragma unroll
    for (int a1 = 0; a1 <= 5 - a0; ++a1) {
      float pa2 = pa1, pb2 = pb1;
#pragma unroll
      for (int a2 = 0; a2 <= 5 - a0 - a1; ++a2) {
        float pa3 = pa2, pb3 = pb2;
#pragma unroll
        for (int a3 = 0; a3 <= 5 - a0 - a1 - a2; ++a3) {
          float w = wcoef(a0, a1, a2, a3);  // literal after unroll
          float wa = pa3 * w, wb = pb3 * w;
          float4 M4 = *(const float4*)&Mw[idx][0];
          float M5 = Mw[idx][4];
          nA0 += wa * M4.x; nA1 += wa * M4.y;
          nA2 += wa * M4.z; nA3 += wa * M4.w;
          dA += wa * M5;
          nB0 += wb * M4.x; nB1 += wb * M4.y;
          nB2 += wb * M4.z; nB3 += wb * M4.w;
          dB += wb * M5;
          ++idx;
          pa3 *= xa3; pb3 *= xb3;
        }
        pa2 *= xa2; pb2 *= xb2;
      }
      pa1 *= xa1; pb1 *= xb1;
    }
    pa0 *= xa0; pb0 *= xb0;
  }

  const int b_ = bh >> 5, head = bh & 31;
  {
    float inv = 1.0f / dA;
    union { fp16x2 p[2]; uint2 u; } res;
    res.p[0] = __builtin_amdgcn_cvt_pkrtz(nA0 * inv, nA1 * inv);
    res.p[1] = __builtin_amdgcn_cvt_pkrtz(nA2 * inv, nA3 * inv);
    o16u2[(((b_ << 10) + q0) << 5) + head] = res.u;
  }
  {
    float inv = 1.0f / dB;
    union { fp16x2 p[2]; uint2 u; } res;
    res.p[0] = __builtin_amdgcn_cvt_pkrtz(nB0 * inv, nB1 * inv);
    res.p[1] = __builtin_amdgcn_cvt_pkrtz(nB2 * inv, nB3 * inv);
    o16u2[(((b_ << 10) + q0 + 256) << 5) + head] = res.u;
  }
}

// ---------------------------------------------------------------------------
// K3: combine GEMM out[8192][128] = o16 @ W^T via mfma_f32_16x16x32_f16.
// (verified R6-R24: ~3 us)
// ---------------------------------------------------------------------------
__global__ __launch_bounds__(256) void combine_kernel(
    const _Float16* __restrict__ o16, const _Float16* __restrict__ wtb,
    float* __restrict__ out) {
  const int lane = threadIdx.x & 63;
  const int wv = threadIdx.x >> 6;
  const int job = blockIdx.x * 4 + wv;  // 0..4095
  const int rt = job >> 3, ct = job & 7;
  const int c = lane & 15, g = lane >> 4;
  const uint4* a4 = (const uint4*)o16;
  const uint4* b4 = (const uint4*)wtb;
  const int arow = (rt << 4) + c;
  union U4H { uint4 u; half8v h; };
  float4v acc = {};
#pragma unroll
  for (int t = 0; t < 4; ++t) {
    U4H ua, ub;
    ua.u = a4[(arow << 4) + (t << 2) + g];
    ub.u = b4[(((t << 2) + g) << 7) + (ct << 4) + c];
    acc = __builtin_amdgcn_mfma_f32_16x16x32_f16(ua.h, ub.h, acc, 0, 0, 0);
  }
  const int orow = (rt << 4) + (g << 2);
  const int ocol = (ct << 4) + c;
#pragma unroll
  for (int reg = 0; reg < 4; ++reg)
    out[(orow + reg) * 128 + ocol] = acc[reg];
}

extern "C" void kernel_launch(void* const* d_in, const int* in_sizes, int n_in,
                              void* d_out, int out_size, void* d_ws,
                              size_t ws_size, hipStream_t stream) {
  const float* x = (const float*)d_in[0];   // [8,1024,128] f32
  const float* qp = (const float*)d_in[1];  // [1,4] f32
  const float* W = (const float*)d_in[2];   // [128,128] f32
  float* out = (float*)d_out;               // [8,1024,128] f32

  char* ws = (char*)d_ws;
  _Float16* h16 = (_Float16*)ws;                 // [256][1024][4] f16 = 2 MB
  float* Mpart = (float*)(ws + (2 << 20));       // [256][2][126][5] f32 ~1.3MB
  _Float16* o16 = (_Float16*)(ws + (6 << 20));   // [8192][128] f16 = 2 MB
  _Float16* wtb = (_Float16*)(ws + (8 << 20));   // [16][128][8] f16 = 32 KB

  qenc_kernel<<<1024, 256, 0, stream>>>((const float4*)x, qp, (uint2*)h16, W,
                                        wtb);
  featM_kernel<<<512, 256, 0, stream>>>(h16, Mpart);
  featC_kernel<<<512, 256, 0, stream>>>(h16, Mpart, (uint2*)o16);
  combine_kernel<<<1024, 256, 0, stream>>>(o16, wtb, out);
}